// Round 1
// baseline (754.094 us; speedup 1.0000x reference)
//
#include <hip/hip_runtime.h>

typedef __attribute__((ext_vector_type(8))) short short8;
typedef __attribute__((ext_vector_type(4))) float floatx4;
typedef unsigned short ushort_t;

// ---------- helpers ----------
__device__ __forceinline__ ushort_t f2bf(float x) {
  union { float f; unsigned int u; } v; v.f = x;
  unsigned int u = v.u;
  return (ushort_t)((u + 0x7FFFu + ((u >> 16) & 1u)) >> 16);  // RNE
}
__device__ __forceinline__ unsigned int pk2(float a, float b) {
  return (unsigned int)f2bf(a) | ((unsigned int)f2bf(b) << 16);
}

// ---------- prep: transpose+convert weights to bf16 ----------
// W1 [512,256] -> W1T [256,512] ; W2 [256,512] -> W2T [512,256]
__global__ void prep_kernel(const float* __restrict__ W1, const float* __restrict__ W2,
                            ushort_t* __restrict__ W1T, ushort_t* __restrict__ W2T) {
  int idx = blockIdx.x * 256 + threadIdx.x;   // 0 .. 131071
  if (idx < 256 * 512) {
    int n = idx >> 9, k = idx & 511;          // W1T[n][k] = W1[k][n]
    W1T[idx] = f2bf(W1[k * 256 + n]);
    int n2 = idx >> 8, k2 = idx & 255;        // W2T[n2][k2] = W2[k2][n2]
    W2T[idx] = f2bf(W2[k2 * 512 + n2]);
  }
}

// ---------- main GEMM: C[M,N] = A[M,K] * B[K,N], B given as BT[N,K] row-major ----------
// 128x128 tile, 4 waves (2x2), each wave 4x4 frags of 16x16, BK=32.
// ABF/BBF: operand already bf16 (else fp32, converted in-register during staging).
// EPI: 0 = store bf16 C ; 1 = relu(C+bias[m]) -> bf16 ; 2 = relu(C+bias[m]) row-summed
//      into gacc[m] (no C store) ; 3 = store fp32 partial at split-K z offset.
template<bool ABF, bool BBF, int EPI>
__global__ __launch_bounds__(256, 2)
void gemm128(const void* __restrict__ Ap, const void* __restrict__ Bp,
             const float* __restrict__ bias, void* __restrict__ Cv,
             float* __restrict__ gacc, const int K, const int N) {
  // LDS layout (quad-major): element (row, k) lives at [(k>>3)*128 + row]*8 + (k&7)
  __shared__ ushort_t Als[4096];
  __shared__ ushort_t Bls[4096];

  const int t = threadIdx.x;
  const int lane = t & 63;
  const int w = t >> 6;
  const int wm = w >> 1, wn = w & 1;
  const int ml = lane & 15, quad = lane >> 4;
  const int m0 = blockIdx.y * 128, n0 = blockIdx.x * 128;
  const int sr = t >> 1, sh = t & 1;         // staging: row, k-half(16)

  const int Kper = K / gridDim.z;
  const int kbeg = blockIdx.z * Kper;

  long aoff = (long)(m0 + sr) * K + kbeg + sh * 16;
  long boff = (long)(n0 + sr) * K + kbeg + sh * 16;

  const float*    Af = (const float*)Ap;
  const ushort_t* Ab = (const ushort_t*)Ap;
  const float*    Bf = (const float*)Bp;
  const ushort_t* Bb = (const ushort_t*)Bp;

  floatx4 acc[4][4] = {};

  const int lw0 = ((2 * sh) * 128 + sr) * 8;      // chunk (quad 2h,   row sr)
  const int lw1 = ((2 * sh + 1) * 128 + sr) * 8;  // chunk (quad 2h+1, row sr)

  for (int kk = 0; kk < Kper; kk += 32) {
    uint4 a0, a1, b0, b1;
    if constexpr (ABF) {
      a0 = *(const uint4*)(Ab + aoff);
      a1 = *(const uint4*)(Ab + aoff + 8);
    } else {
      float4 f0 = *(const float4*)(Af + aoff);
      float4 f1 = *(const float4*)(Af + aoff + 4);
      float4 f2 = *(const float4*)(Af + aoff + 8);
      float4 f3 = *(const float4*)(Af + aoff + 12);
      a0 = make_uint4(pk2(f0.x,f0.y), pk2(f0.z,f0.w), pk2(f1.x,f1.y), pk2(f1.z,f1.w));
      a1 = make_uint4(pk2(f2.x,f2.y), pk2(f2.z,f2.w), pk2(f3.x,f3.y), pk2(f3.z,f3.w));
    }
    if constexpr (BBF) {
      b0 = *(const uint4*)(Bb + boff);
      b1 = *(const uint4*)(Bb + boff + 8);
    } else {
      float4 g0 = *(const float4*)(Bf + boff);
      float4 g1 = *(const float4*)(Bf + boff + 4);
      float4 g2 = *(const float4*)(Bf + boff + 8);
      float4 g3 = *(const float4*)(Bf + boff + 12);
      b0 = make_uint4(pk2(g0.x,g0.y), pk2(g0.z,g0.w), pk2(g1.x,g1.y), pk2(g1.z,g1.w));
      b1 = make_uint4(pk2(g2.x,g2.y), pk2(g2.z,g2.w), pk2(g3.x,g3.y), pk2(g3.z,g3.w));
    }
    __syncthreads();                    // protect LDS against previous iter's reads
    *(uint4*)(Als + lw0) = a0;
    *(uint4*)(Als + lw1) = a1;
    *(uint4*)(Bls + lw0) = b0;
    *(uint4*)(Bls + lw1) = b1;
    __syncthreads();

    short8 av[4], bv[4];
#pragma unroll
    for (int f = 0; f < 4; ++f) {
      av[f] = *(const short8*)(Als + (quad * 128 + wm * 64 + f * 16 + ml) * 8);
      bv[f] = *(const short8*)(Bls + (quad * 128 + wn * 64 + f * 16 + ml) * 8);
    }
#pragma unroll
    for (int fm = 0; fm < 4; ++fm)
#pragma unroll
      for (int fn = 0; fn < 4; ++fn)
        acc[fm][fn] = __builtin_amdgcn_mfma_f32_16x16x32_bf16(av[fm], bv[fn], acc[fm][fn], 0, 0, 0);

    aoff += 32;
    boff += 32;
  }

  // ---------------- epilogue ----------------
  if constexpr (EPI == 2) {
    // relu(acc + bias[m]) row-sum over n -> atomicAdd gacc[m]
#pragma unroll
    for (int fm = 0; fm < 4; ++fm) {
      int rowb = m0 + wm * 64 + fm * 16 + quad * 4;
#pragma unroll
      for (int r = 0; r < 4; ++r) {
        float bb = bias[rowb + r];
        float s = 0.f;
#pragma unroll
        for (int fn = 0; fn < 4; ++fn)
          s += fmaxf(acc[fm][fn][r] + bb, 0.f);
        s += __shfl_xor(s, 1);
        s += __shfl_xor(s, 2);
        s += __shfl_xor(s, 4);
        s += __shfl_xor(s, 8);
        if (ml == 0) atomicAdd(gacc + rowb + r, s);
      }
    }
  } else if constexpr (EPI == 3) {
    float* Cf = (float*)Cv;
    const long zoff = (long)blockIdx.z * ((long)gridDim.y * 128) * N;
#pragma unroll
    for (int fm = 0; fm < 4; ++fm)
#pragma unroll
      for (int fn = 0; fn < 4; ++fn) {
        int gm = m0 + wm * 64 + fm * 16 + quad * 4;
        int gn = n0 + wn * 64 + fn * 16 + ml;
#pragma unroll
        for (int r = 0; r < 4; ++r)
          Cf[zoff + (long)(gm + r) * N + gn] = acc[fm][fn][r];
      }
  } else {
    ushort_t* C = (ushort_t*)Cv;
#pragma unroll
    for (int fm = 0; fm < 4; ++fm)
#pragma unroll
      for (int fn = 0; fn < 4; ++fn) {
        int gm = m0 + wm * 64 + fm * 16 + quad * 4;
        int gn = n0 + wn * 64 + fn * 16 + ml;
#pragma unroll
        for (int r = 0; r < 4; ++r) {
          float v = acc[fm][fn][r];
          if constexpr (EPI == 1) v = fmaxf(v + bias[gm + r], 0.f);
          C[(long)(gm + r) * N + gn] = f2bf(v);
        }
      }
  }
}

// ---------- split-K reduce: out_bf16 = [relu(p0+p1+bias[row])] ----------
template<bool RELU_BIAS>
__global__ void reduce2_kernel(const float* __restrict__ p, ushort_t* __restrict__ out,
                               const float* __restrict__ bias, const int rowShift,
                               const long total4, const long halfOff) {
  long i = (long)blockIdx.x * blockDim.x + threadIdx.x;
  if (i >= total4) return;
  long e = i * 4;
  float4 a = *(const float4*)(p + e);
  float4 b = *(const float4*)(p + halfOff + e);
  float v0 = a.x + b.x, v1 = a.y + b.y, v2 = a.z + b.z, v3 = a.w + b.w;
  if constexpr (RELU_BIAS) {
    float bb = bias[e >> rowShift];
    v0 = fmaxf(v0 + bb, 0.f); v1 = fmaxf(v1 + bb, 0.f);
    v2 = fmaxf(v2 + bb, 0.f); v3 = fmaxf(v3 + bb, 0.f);
  }
  uint2 o;
  o.x = pk2(v0, v1);
  o.y = pk2(v2, v3);
  *(uint2*)(out + e) = o;
}

// ---------- tail: selu(mean) | fc1 | attention | log_softmax (exact fp32) ----------
__global__ void tail_kernel(const float* __restrict__ gacc, const float* __restrict__ sub_fea,
                            const float* __restrict__ fc1_W, const float* __restrict__ fc1_b,
                            const float* __restrict__ att_W, const float* __restrict__ att_a,
                            const float* __restrict__ att_b, float* __restrict__ out) {
  __shared__ float z[768];
  __shared__ float sc[8];
  __shared__ float alpha[8];
  __shared__ float outsh[10];
  const int t = threadIdx.x;  // 256 threads

  // g = selu(colmean(h2)) -> z[0:512]
  for (int j = t; j < 512; j += 256) {
    float x = gacc[j] * (1.0f / 8192.0f);
    const float scale = 1.0507009873554805f, al = 1.6732632423543772f;
    z[j] = x > 0.f ? scale * x : scale * al * (expf(x) - 1.0f);
  }
  // x_ext = sub_fea @ fc1_W + fc1_b -> z[512:768]
  {
    float a = fc1_b[t];
    for (int i = 0; i < 128; ++i) a += sub_fea[i] * fc1_W[i * 256 + t];
    z[512 + t] = a;
  }
  if (t < 10) outsh[t] = 0.f;
  __syncthreads();

  // scores: 32 threads per head
  {
    int h = t >> 5, ln = t & 31;
    float p = 0.f;
    for (int i = ln; i < 768; i += 32) p += z[i] * att_a[h * 768 + i];
    for (int m = 16; m; m >>= 1) p += __shfl_down(p, m, 32);
    if (ln == 0) sc[h] = p;
  }
  __syncthreads();
  if (t == 0) {
    float mx = sc[0];
    for (int h = 1; h < 8; ++h) mx = fmaxf(mx, sc[h]);
    float s = 0.f, e[8];
    for (int h = 0; h < 8; ++h) { e[h] = expf(sc[h] - mx); s += e[h]; }
    for (int h = 0; h < 8; ++h) alpha[h] = e[h] / s;
  }
  __syncthreads();

  // out[o] = sum_i z_i * sum_h alpha_h W[h,i,o]
  float p[10];
#pragma unroll
  for (int o = 0; o < 10; ++o) p[o] = 0.f;
  for (int i = t; i < 768; i += 256) {
    float zi = z[i];
    for (int h = 0; h < 8; ++h) {
      float za = zi * alpha[h];
      const float* wp = att_W + (h * 768 + i) * 10;
#pragma unroll
      for (int o = 0; o < 10; ++o) p[o] += za * wp[o];
    }
  }
#pragma unroll
  for (int o = 0; o < 10; ++o) atomicAdd(&outsh[o], p[o]);
  __syncthreads();
  if (t == 0) {
    float v[10], mx = -1e30f;
    for (int o = 0; o < 10; ++o) { v[o] = outsh[o] + att_b[o]; mx = fmaxf(mx, v[o]); }
    float s = 0.f;
    for (int o = 0; o < 10; ++o) s += expf(v[o] - mx);
    float lse = logf(s) + mx;
    for (int o = 0; o < 10; ++o) out[o] = v[o] - lse;
  }
}

// ---------- launch ----------
extern "C" void kernel_launch(void* const* d_in, const int* in_sizes, int n_in,
                              void* d_out, int out_size, void* d_ws, size_t ws_size,
                              hipStream_t stream) {
  const float* x       = (const float*)d_in[0];   // [8192,512]
  const float* adj     = (const float*)d_in[1];   // [8192,8192]
  const float* sub_fea = (const float*)d_in[2];   // [1,128]
  const float* gc1_W   = (const float*)d_in[3];   // [512,256]
  const float* gc1_b   = (const float*)d_in[4];   // [256]
  const float* gc2_W   = (const float*)d_in[5];   // [256,512]
  const float* gc2_b   = (const float*)d_in[6];   // [512]
  const float* fc1_W   = (const float*)d_in[7];   // [128,256]
  const float* fc1_b   = (const float*)d_in[8];   // [256]
  const float* att_W   = (const float*)d_in[9];   // [8,768,10]
  const float* att_a   = (const float*)d_in[10];  // [8,768]
  const float* att_b   = (const float*)d_in[11];  // [10]
  float* out = (float*)d_out;

  char* ws = (char*)d_ws;
  ushort_t* t1T  = (ushort_t*)(ws);                               // [256,8192] bf16, 4 MB
  ushort_t* h1T  = (ushort_t*)(ws + (4u  << 20));                 // [256,8192] bf16, 4 MB
  ushort_t* P    = (ushort_t*)(ws + (8u  << 20));                 // [8192,256] bf16, 4 MB
  float*    part = (float*)   (ws + (12u << 20));                 // 2 x 2M fp32, 16 MB
  ushort_t* W1T  = (ushort_t*)(ws + (28u << 20));                 // [256,512] bf16
  ushort_t* W2T  = (ushort_t*)(ws + (28u << 20) + 262144);        // [512,256] bf16
  float*    gacc = (float*)   (ws + (28u << 20) + 524288);        // [512] fp32

  hipMemsetAsync(gacc, 0, 512 * sizeof(float), stream);
  prep_kernel<<<512, 256, 0, stream>>>(gc1_W, gc2_W, W1T, W2T);

  // L1a: t1T[256,8192] = W1T[256,512] * x^T   (BT = x)
  gemm128<true, false, 0><<<dim3(64, 2, 1), 256, 0, stream>>>(W1T, x, nullptr, t1T, nullptr, 512, 8192);

  // L1b: s1T[256,8192] = t1T * adj^T (BT = adj), split-K=2 -> fp32 partials
  gemm128<true, false, 3><<<dim3(64, 2, 2), 256, 0, stream>>>(t1T, adj, nullptr, part, nullptr, 8192, 8192);
  // h1T = relu(s1T + gc1_b[row]) ; row = e >> 13
  reduce2_kernel<true><<<2048, 256, 0, stream>>>(part, h1T, gc1_b, 13, 524288L, 256L * 8192L);

  // L2a: P[8192,256] = adj * h1 (BT = h1T), split-K=2
  gemm128<false, true, 3><<<dim3(2, 64, 2), 256, 0, stream>>>(adj, h1T, nullptr, part, nullptr, 8192, 256);
  reduce2_kernel<false><<<2048, 256, 0, stream>>>(part, P, nullptr, 0, 524288L, 8192L * 256L);

  // L2b: t2T[512,8192] = W2T * P^T (BT = P); epilogue relu(+gc2_b) row-sum -> gacc
  gemm128<true, true, 2><<<dim3(64, 4, 1), 256, 0, stream>>>(W2T, P, gc2_b, nullptr, gacc, 256, 8192);

  tail_kernel<<<1, 256, 0, stream>>>(gacc, sub_fea, fc1_W, fc1_b, att_W, att_a, att_b, out);
}

// Round 2
// 688.148 us; speedup vs baseline: 1.0958x; 1.0958x over previous
//
#include <hip/hip_runtime.h>

typedef __attribute__((ext_vector_type(8))) short short8;
typedef __attribute__((ext_vector_type(4))) float floatx4;
typedef unsigned short ushort_t;

// ---------- helpers ----------
__device__ __forceinline__ ushort_t f2bf(float x) {
  union { float f; unsigned int u; } v; v.f = x;
  unsigned int u = v.u;
  return (ushort_t)((u + 0x7FFFu + ((u >> 16) & 1u)) >> 16);  // RNE
}
__device__ __forceinline__ unsigned int pk2(float a, float b) {
  return (unsigned int)f2bf(a) | ((unsigned int)f2bf(b) << 16);
}

// ---------- prep: transpose+convert weights to bf16 ----------
__global__ void prep_kernel(const float* __restrict__ W1, const float* __restrict__ W2,
                            ushort_t* __restrict__ W1T, ushort_t* __restrict__ W2T) {
  int idx = blockIdx.x * 256 + threadIdx.x;   // 0 .. 131071
  if (idx < 256 * 512) {
    int n = idx >> 9, k = idx & 511;          // W1T[n][k] = W1[k][n]
    W1T[idx] = f2bf(W1[k * 256 + n]);
    int n2 = idx >> 8, k2 = idx & 255;        // W2T[n2][k2] = W2[k2][n2]
    W2T[idx] = f2bf(W2[k2 * 512 + n2]);
  }
}

// ---------- main GEMM: C[M,N] = A[M,K] * B[K,N], B given as BT[N,K] row-major ----------
// 128x128 tile, 4 waves (2x2), each wave 4x4 frags of 16x16, BK=32.
// Software-pipelined: next K-tile's global loads issued between LDS-write and
// the compute barrier, so load latency hides behind MFMA phase + barriers.
// EPI: 0 = store bf16 C ; 1 = relu(C+bias[m]) -> bf16 ; 2 = relu(C+bias[m]) row-summed
//      into gacc[m] (no C store) ; 3 = store fp32 partial at split-K z offset.
template<bool ABF, bool BBF, int EPI>
__global__ __launch_bounds__(256, 2)
void gemm128(const void* __restrict__ Ap, const void* __restrict__ Bp,
             const float* __restrict__ bias, void* __restrict__ Cv,
             float* __restrict__ gacc, const int K, const int N) {
  // LDS layout (quad-major): element (row, k) lives at [(k>>3)*128 + row]*8 + (k&7)
  __shared__ ushort_t Als[4096];
  __shared__ ushort_t Bls[4096];

  const int t = threadIdx.x;
  const int lane = t & 63;
  const int w = t >> 6;
  const int wm = w >> 1, wn = w & 1;
  const int ml = lane & 15, quad = lane >> 4;
  const int m0 = blockIdx.y * 128, n0 = blockIdx.x * 128;
  const int sr = t >> 1, sh = t & 1;         // staging: row, k-half(16)

  const int Kper = K / gridDim.z;
  const int kbeg = blockIdx.z * Kper;

  long aoff = (long)(m0 + sr) * K + kbeg + sh * 16;
  long boff = (long)(n0 + sr) * K + kbeg + sh * 16;

  const float*    Af = (const float*)Ap;
  const ushort_t* Ab = (const ushort_t*)Ap;
  const float*    Bf = (const float*)Bp;
  const ushort_t* Bb = (const ushort_t*)Bp;

  floatx4 acc[4][4] = {};

  const int lw0 = ((2 * sh) * 128 + sr) * 8;      // chunk (quad 2h,   row sr)
  const int lw1 = ((2 * sh + 1) * 128 + sr) * 8;  // chunk (quad 2h+1, row sr)

  // staging registers (one K-tile in flight)
  uint4 aU0, aU1, bU0, bU1;
  float4 aF0, aF1, aF2, aF3, bF0, bF1, bF2, bF3;

  auto loadA = [&]() {
    if constexpr (ABF) {
      aU0 = *(const uint4*)(Ab + aoff);
      aU1 = *(const uint4*)(Ab + aoff + 8);
    } else {
      aF0 = *(const float4*)(Af + aoff);
      aF1 = *(const float4*)(Af + aoff + 4);
      aF2 = *(const float4*)(Af + aoff + 8);
      aF3 = *(const float4*)(Af + aoff + 12);
    }
    aoff += 32;
  };
  auto loadB = [&]() {
    if constexpr (BBF) {
      bU0 = *(const uint4*)(Bb + boff);
      bU1 = *(const uint4*)(Bb + boff + 8);
    } else {
      bF0 = *(const float4*)(Bf + boff);
      bF1 = *(const float4*)(Bf + boff + 4);
      bF2 = *(const float4*)(Bf + boff + 8);
      bF3 = *(const float4*)(Bf + boff + 12);
    }
    boff += 32;
  };

  // prologue: tile 0 in flight
  loadA();
  loadB();

  for (int kk = 0; kk < Kper; kk += 32) {
    // convert current tile to packed bf16 (waits on the in-flight loads)
    uint4 a0, a1, b0, b1;
    if constexpr (ABF) { a0 = aU0; a1 = aU1; }
    else {
      a0 = make_uint4(pk2(aF0.x,aF0.y), pk2(aF0.z,aF0.w), pk2(aF1.x,aF1.y), pk2(aF1.z,aF1.w));
      a1 = make_uint4(pk2(aF2.x,aF2.y), pk2(aF2.z,aF2.w), pk2(aF3.x,aF3.y), pk2(aF3.z,aF3.w));
    }
    if constexpr (BBF) { b0 = bU0; b1 = bU1; }
    else {
      b0 = make_uint4(pk2(bF0.x,bF0.y), pk2(bF0.z,bF0.w), pk2(bF1.x,bF1.y), pk2(bF1.z,bF1.w));
      b1 = make_uint4(pk2(bF2.x,bF2.y), pk2(bF2.z,bF2.w), pk2(bF3.x,bF3.y), pk2(bF3.z,bF3.w));
    }
    __syncthreads();                    // prior iter's LDS reads complete
    *(uint4*)(Als + lw0) = a0;
    *(uint4*)(Als + lw1) = a1;
    *(uint4*)(Bls + lw0) = b0;
    *(uint4*)(Bls + lw1) = b1;
    if (kk + 32 < Kper) {               // issue next tile NOW; lands during compute
      loadA();
      loadB();
    }
    __syncthreads();

    short8 av[4], bv[4];
#pragma unroll
    for (int f = 0; f < 4; ++f) {
      av[f] = *(const short8*)(Als + (quad * 128 + wm * 64 + f * 16 + ml) * 8);
      bv[f] = *(const short8*)(Bls + (quad * 128 + wn * 64 + f * 16 + ml) * 8);
    }
#pragma unroll
    for (int fm = 0; fm < 4; ++fm)
#pragma unroll
      for (int fn = 0; fn < 4; ++fn)
        acc[fm][fn] = __builtin_amdgcn_mfma_f32_16x16x32_bf16(av[fm], bv[fn], acc[fm][fn], 0, 0, 0);
  }

  // ---------------- epilogue ----------------
  if constexpr (EPI == 2) {
    // relu(acc + bias[m]) row-sum over n -> atomicAdd gacc[m]
#pragma unroll
    for (int fm = 0; fm < 4; ++fm) {
      int rowb = m0 + wm * 64 + fm * 16 + quad * 4;
#pragma unroll
      for (int r = 0; r < 4; ++r) {
        float bb = bias[rowb + r];
        float s = 0.f;
#pragma unroll
        for (int fn = 0; fn < 4; ++fn)
          s += fmaxf(acc[fm][fn][r] + bb, 0.f);
        s += __shfl_xor(s, 1);
        s += __shfl_xor(s, 2);
        s += __shfl_xor(s, 4);
        s += __shfl_xor(s, 8);
        if (ml == 0) atomicAdd(gacc + rowb + r, s);
      }
    }
  } else if constexpr (EPI == 3) {
    float* Cf = (float*)Cv;
    const long zoff = (long)blockIdx.z * ((long)gridDim.y * 128) * N;
#pragma unroll
    for (int fm = 0; fm < 4; ++fm)
#pragma unroll
      for (int fn = 0; fn < 4; ++fn) {
        int gm = m0 + wm * 64 + fm * 16 + quad * 4;
        int gn = n0 + wn * 64 + fn * 16 + ml;
#pragma unroll
        for (int r = 0; r < 4; ++r)
          Cf[zoff + (long)(gm + r) * N + gn] = acc[fm][fn][r];
      }
  } else {
    ushort_t* C = (ushort_t*)Cv;
#pragma unroll
    for (int fm = 0; fm < 4; ++fm)
#pragma unroll
      for (int fn = 0; fn < 4; ++fn) {
        int gm = m0 + wm * 64 + fm * 16 + quad * 4;
        int gn = n0 + wn * 64 + fn * 16 + ml;
#pragma unroll
        for (int r = 0; r < 4; ++r) {
          float v = acc[fm][fn][r];
          if constexpr (EPI == 1) v = fmaxf(v + bias[gm + r], 0.f);
          C[(long)(gm + r) * N + gn] = f2bf(v);
        }
      }
  }
}

// ---------- split-K reduce: out_bf16 = [relu(sum_z p_z + bias[row])] ----------
template<bool RELU_BIAS>
__global__ void reduceZ_kernel(const float* __restrict__ p, ushort_t* __restrict__ out,
                               const float* __restrict__ bias, const int rowShift,
                               const long total4, const long zstride, const int Z) {
  long i = (long)blockIdx.x * blockDim.x + threadIdx.x;
  if (i >= total4) return;
  long e = i * 4;
  float4 s = *(const float4*)(p + e);
  for (int z = 1; z < Z; ++z) {
    float4 b = *(const float4*)(p + (long)z * zstride + e);
    s.x += b.x; s.y += b.y; s.z += b.z; s.w += b.w;
  }
  if constexpr (RELU_BIAS) {
    float bb = bias[e >> rowShift];
    s.x = fmaxf(s.x + bb, 0.f); s.y = fmaxf(s.y + bb, 0.f);
    s.z = fmaxf(s.z + bb, 0.f); s.w = fmaxf(s.w + bb, 0.f);
  }
  uint2 o;
  o.x = pk2(s.x, s.y);
  o.y = pk2(s.z, s.w);
  *(uint2*)(out + e) = o;
}

// ---------- tail: selu(mean) | fc1 | attention | log_softmax (exact fp32) ----------
__global__ void tail_kernel(const float* __restrict__ gacc, const float* __restrict__ sub_fea,
                            const float* __restrict__ fc1_W, const float* __restrict__ fc1_b,
                            const float* __restrict__ att_W, const float* __restrict__ att_a,
                            const float* __restrict__ att_b, float* __restrict__ out) {
  __shared__ float z[768];
  __shared__ float sc[8];
  __shared__ float alpha[8];
  __shared__ float outsh[10];
  const int t = threadIdx.x;  // 256 threads

  for (int j = t; j < 512; j += 256) {
    float x = gacc[j] * (1.0f / 8192.0f);
    const float scale = 1.0507009873554805f, al = 1.6732632423543772f;
    z[j] = x > 0.f ? scale * x : scale * al * (expf(x) - 1.0f);
  }
  {
    float a = fc1_b[t];
    for (int i = 0; i < 128; ++i) a += sub_fea[i] * fc1_W[i * 256 + t];
    z[512 + t] = a;
  }
  if (t < 10) outsh[t] = 0.f;
  __syncthreads();

  {
    int h = t >> 5, ln = t & 31;
    float p = 0.f;
    for (int i = ln; i < 768; i += 32) p += z[i] * att_a[h * 768 + i];
    for (int m = 16; m; m >>= 1) p += __shfl_down(p, m, 32);
    if (ln == 0) sc[h] = p;
  }
  __syncthreads();
  if (t == 0) {
    float mx = sc[0];
    for (int h = 1; h < 8; ++h) mx = fmaxf(mx, sc[h]);
    float s = 0.f, e[8];
    for (int h = 0; h < 8; ++h) { e[h] = expf(sc[h] - mx); s += e[h]; }
    for (int h = 0; h < 8; ++h) alpha[h] = e[h] / s;
  }
  __syncthreads();

  float p[10];
#pragma unroll
  for (int o = 0; o < 10; ++o) p[o] = 0.f;
  for (int i = t; i < 768; i += 256) {
    float zi = z[i];
    for (int h = 0; h < 8; ++h) {
      float za = zi * alpha[h];
      const float* wp = att_W + (h * 768 + i) * 10;
#pragma unroll
      for (int o = 0; o < 10; ++o) p[o] += za * wp[o];
    }
  }
#pragma unroll
  for (int o = 0; o < 10; ++o) atomicAdd(&outsh[o], p[o]);
  __syncthreads();
  if (t == 0) {
    float v[10], mx = -1e30f;
    for (int o = 0; o < 10; ++o) { v[o] = outsh[o] + att_b[o]; mx = fmaxf(mx, v[o]); }
    float s = 0.f;
    for (int o = 0; o < 10; ++o) s += expf(v[o] - mx);
    float lse = logf(s) + mx;
    for (int o = 0; o < 10; ++o) out[o] = v[o] - lse;
  }
}

// ---------- launch ----------
extern "C" void kernel_launch(void* const* d_in, const int* in_sizes, int n_in,
                              void* d_out, int out_size, void* d_ws, size_t ws_size,
                              hipStream_t stream) {
  const float* x       = (const float*)d_in[0];   // [8192,512]
  const float* adj     = (const float*)d_in[1];   // [8192,8192]
  const float* sub_fea = (const float*)d_in[2];   // [1,128]
  const float* gc1_W   = (const float*)d_in[3];   // [512,256]
  const float* gc1_b   = (const float*)d_in[4];   // [256]
  const float* gc2_W   = (const float*)d_in[5];   // [256,512]
  const float* gc2_b   = (const float*)d_in[6];   // [512]
  const float* fc1_W   = (const float*)d_in[7];   // [128,256]
  const float* fc1_b   = (const float*)d_in[8];   // [256]
  const float* att_W   = (const float*)d_in[9];   // [8,768,10]
  const float* att_a   = (const float*)d_in[10];  // [8,768]
  const float* att_b   = (const float*)d_in[11];  // [10]
  float* out = (float*)d_out;

  // split-K factor for the two adj-GEMMs: 8 if workspace allows the partials
  const int zbig = (ws_size >= (size_t)(90u << 20)) ? 8 : 2;

  char* ws = (char*)d_ws;
  const size_t MB = 1u << 20;
  ushort_t* t1T  = (ushort_t*)(ws);                  // [256,8192] bf16, 4 MB
  ushort_t* h1T  = (ushort_t*)(ws + 4 * MB);         // [256,8192] bf16, 4 MB
  ushort_t* P    = (ushort_t*)(ws + 8 * MB);         // [8192,256] bf16, 4 MB
  float*    part = (float*)   (ws + 12 * MB);        // zbig x 2M fp32
  size_t    partBytes = (size_t)zbig * 2097152 * 4;
  ushort_t* W1T  = (ushort_t*)(ws + 12 * MB + partBytes);
  ushort_t* W2T  = (ushort_t*)(ws + 12 * MB + partBytes + 262144);
  float*    gacc = (float*)   (ws + 12 * MB + partBytes + 524288);

  hipMemsetAsync(gacc, 0, 512 * sizeof(float), stream);
  prep_kernel<<<512, 256, 0, stream>>>(gc1_W, gc2_W, W1T, W2T);

  // L1a: t1T[256,8192] = W1T[256,512] * x^T   (BT = x), split-K=2
  gemm128<true, false, 3><<<dim3(64, 2, 2), 256, 0, stream>>>(W1T, x, nullptr, part, nullptr, 512, 8192);
  reduceZ_kernel<false><<<2048, 256, 0, stream>>>(part, t1T, nullptr, 0, 524288L, 2097152L, 2);

  // L1b: s1T[256,8192] = t1T * adj^T (BT = adj), split-K=zbig -> fp32 partials
  gemm128<true, false, 3><<<dim3(64, 2, zbig), 256, 0, stream>>>(t1T, adj, nullptr, part, nullptr, 8192, 8192);
  // h1T = relu(s1T + gc1_b[row]) ; row = e >> 13
  reduceZ_kernel<true><<<2048, 256, 0, stream>>>(part, h1T, gc1_b, 13, 524288L, 2097152L, zbig);

  // L2a: P[8192,256] = adj * h1 (BT = h1T), split-K=zbig
  gemm128<false, true, 3><<<dim3(2, 64, zbig), 256, 0, stream>>>(adj, h1T, nullptr, part, nullptr, 8192, 256);
  reduceZ_kernel<false><<<2048, 256, 0, stream>>>(part, P, nullptr, 0, 524288L, 2097152L, zbig);

  // L2b: t2T[512,8192] = W2T * P^T (BT = P); epilogue relu(+gc2_b) row-sum -> gacc
  gemm128<true, true, 2><<<dim3(64, 4, 1), 256, 0, stream>>>(W2T, P, gc2_b, nullptr, gacc, 256, 8192);

  tail_kernel<<<1, 256, 0, stream>>>(gacc, sub_fea, fc1_W, fc1_b, att_W, att_a, att_b, out);
}